// Round 8
// baseline (489.611 us; speedup 1.0000x reference)
//
#include <hip/hip_runtime.h>

#define N_NODES 8192
#define HIDDEN 256
#define OUT_DIM 16
#define CAP 128            // max neighbors stored; binomial max deg ~66 << 128
#define NBLK 1024          // 4 blocks/CU x 256 CUs: all co-resident (launch_bounds)
#define RPB 8              // rows/nodes per block
#define NBAR 5             // barrier ids: 0 A->B, 1 B->C, 2 C->E fast, 3/4 slow

// Software grid barrier: every block drains its stores (syncthreads emits
// vmcnt(0)), release-fences its XCD, then bumps a device-scope counter.
// Counters are zeroed by k_reset each call (ws state is stale/poisoned).
__device__ __forceinline__ void gridbar(int* ctr) {
    __syncthreads();
    if (threadIdx.x == 0) {
        __threadfence();
        __hip_atomic_fetch_add(ctr, 1, __ATOMIC_ACQ_REL, __HIP_MEMORY_SCOPE_AGENT);
        while (__hip_atomic_load(ctr, __ATOMIC_ACQUIRE, __HIP_MEMORY_SCOPE_AGENT) < NBLK)
            __builtin_amdgcn_s_sleep(1);
        __threadfence();
    }
    __syncthreads();
}

// ---------------- K0: zero barrier counters + pooled ------------------------
__global__ void k_reset(int* __restrict__ barctr, float* __restrict__ pooled) {
    const int t = threadIdx.x;     // 256
    if (t < NBAR * 32) barctr[t] = 0;   // counters spaced 128 B apart
    pooled[t] = 0.0f;
}

// ---------------- K_all: whole GNN, one persistent kernel -------------------
__global__ __launch_bounds__(256, 4)
void k_all(const float* __restrict__ adj, const float* __restrict__ W1,
           const float* __restrict__ b1, const float* __restrict__ W2,
           const float* __restrict__ b2, const float* __restrict__ Wfc,
           const float* __restrict__ bfc,
           int* __restrict__ cnt, int* __restrict__ nbr,
           float* __restrict__ s, float* __restrict__ tt,
           float* __restrict__ v, float* __restrict__ pooled,
           float* __restrict__ g, int* __restrict__ barctr,
           float* __restrict__ out)
{
    const int t = threadIdx.x;         // 256
    const int bid = blockIdx.x;        // 1024
    const int lane = t & 63;
    const int w = t >> 6;              // wave 0..3

    __shared__ float sm[2048];         // 8 KB, reused per phase
    __shared__ int scnt;
    __shared__ int nzs;

    // ---------------- Phase A: dense row scan -> CSR (R2-proven) ------------
    for (int r = 0; r < RPB; ++r) {
        const int i = bid * RPB + r;
        if (t == 0) scnt = 0;
        __syncthreads();
        const uint4* row = (const uint4*)(adj + (size_t)i * N_NODES);
        #pragma unroll
        for (int c8 = 0; c8 < N_NODES / 4 / 256; ++c8) {   // 8 iterations
            uint4 vv = row[c8 * 256 + t];
            int base = (c8 * 256 + t) * 4;
            if (vv.x | vv.y | vv.z | vv.w) {   // entries are exactly 0.0f/1.0f
                if (vv.x && base + 0 != i) { int p = atomicAdd(&scnt, 1); if (p < CAP) nbr[(size_t)i * CAP + p] = base + 0; }
                if (vv.y && base + 1 != i) { int p = atomicAdd(&scnt, 1); if (p < CAP) nbr[(size_t)i * CAP + p] = base + 1; }
                if (vv.z && base + 2 != i) { int p = atomicAdd(&scnt, 1); if (p < CAP) nbr[(size_t)i * CAP + p] = base + 2; }
                if (vv.w && base + 3 != i) { int p = atomicAdd(&scnt, 1); if (p < CAP) nbr[(size_t)i * CAP + p] = base + 3; }
            }
        }
        __syncthreads();
        if (t == 0) cnt[i] = scnt < CAP ? scnt : CAP;
    }
    gridbar(&barctr[0 * 32]);

    // ---------------- Phase B: s,tt per node-wave; v (blocks 0..15); flag ---
    if (t == 0) nzs = 0;
    __syncthreads();
    if (b1[t] != 0.0f) atomicOr(&nzs, 1);   // per-block local flag, no global dep
    #pragma unroll
    for (int n = 0; n < 2; ++n) {
        const int i = bid * RPB + w * 2 + n;
        const int c = cnt[i];
        const float di = rsqrtf((float)(c + 1));   // +1 self loop
        float p = 0.0f;
        for (int k = lane; k < c; k += 64)
            p += rsqrtf((float)(cnt[nbr[(size_t)i * CAP + k]] + 1));
        #pragma unroll
        for (int off = 32; off > 0; off >>= 1) p += __shfl_down(p, off);
        if (lane == 0) { const float si = di * (di + p); s[i] = si; tt[i] = di * si; }
    }
    if (bid < 16) {      // v[c] = sum_k relu(W1[k]) * W2[k][c]; 16 cols/block
        const int kg = t >> 4, cl = t & 15, c = bid * 16 + cl;
        float partial = 0.0f;
        for (int k = kg; k < HIDDEN; k += 16)
            partial += fmaxf(W1[k], 0.0f) * W2[(size_t)k * HIDDEN + c];
        __syncthreads();
        sm[t] = partial;
        __syncthreads();
        if (t < 16) {
            float acc = 0.0f;
            #pragma unroll
            for (int gg = 0; gg < 16; ++gg) acc += sm[gg * 16 + t];
            v[bid * 16 + t] = acc;
        }
    }
    gridbar(&barctr[1 * 32]);
    const int fastf = (nzs == 0);      // uniform across all blocks

    if (fastf) {
        // ------------- Phase C fast: q per node-wave; atomic pool -----------
        float* qsh = sm;
        #pragma unroll
        for (int n = 0; n < 2; ++n) {
            const int i = bid * RPB + w * 2 + n;
            const int c = cnt[i];
            const float di = rsqrtf((float)(c + 1));
            float p = 0.0f;
            for (int k = lane; k < c; k += 64) p += tt[nbr[(size_t)i * CAP + k]];
            #pragma unroll
            for (int off = 32; off > 0; off >>= 1) p += __shfl_down(p, off);
            if (lane == 0) qsh[w * 2 + n] = di * (di * s[i] + p);
        }
        __syncthreads();
        const float vc = v[t], bc = b2[t];
        float pp = 0.0f;
        #pragma unroll
        for (int n = 0; n < RPB; ++n) pp += fmaxf(qsh[n] * vc + bc, 0.0f);
        atomicAdd(&pooled[t], pp);     // fire-and-forget, 64 hot lines
        gridbar(&barctr[2 * 32]);
    } else {
        // ------------- SLOW C1: g = relu(s (x) W1 + b1) @ W2 ----------------
        float* hT = sm;                // [256][8] k-major
        const float w1 = W1[t], bb = b1[t];
        #pragma unroll
        for (int r = 0; r < RPB; ++r)
            hT[t * RPB + r] = fmaxf(s[bid * RPB + r] * w1 + bb, 0.0f);
        __syncthreads();
        float acc[RPB];
        #pragma unroll
        for (int r = 0; r < RPB; ++r) acc[r] = 0.0f;
        for (int k = 0; k < HIDDEN; ++k) {
            const float w2 = W2[(size_t)k * HIDDEN + t];
            const float4 h0 = *(const float4*)&hT[k * RPB + 0];
            const float4 h1 = *(const float4*)&hT[k * RPB + 4];
            acc[0] += h0.x * w2;  acc[1] += h0.y * w2;  acc[2] += h0.z * w2;  acc[3] += h0.w * w2;
            acc[4] += h1.x * w2;  acc[5] += h1.y * w2;  acc[6] += h1.z * w2;  acc[7] += h1.w * w2;
        }
        #pragma unroll
        for (int r = 0; r < RPB; ++r)
            g[(size_t)(bid * RPB + r) * HIDDEN + t] = acc[r];
        gridbar(&barctr[3 * 32]);
        // ------------- SLOW C2: aggregate + bias + relu + atomic pool -------
        const float bc = b2[t];
        float pool = 0.0f;
        for (int n = 0; n < RPB; ++n) {
            const int i = bid * RPB + n;
            const int c = cnt[i];
            const float di = rsqrtf((float)(c + 1));
            float val = di * g[(size_t)i * HIDDEN + t];
            const int* nb = nbr + (size_t)i * CAP;
            for (int k = 0; k < c; ++k) {
                const int j = nb[k];
                val += rsqrtf((float)(cnt[j] + 1)) * g[(size_t)j * HIDDEN + t];
            }
            pool += fmaxf(di * val + bc, 0.0f);
        }
        atomicAdd(&pooled[t], pool);
        gridbar(&barctr[4 * 32]);
    }

    // ---------------- Phase E: out = pooled @ Wfc + bfc (block 0) -----------
    if (bid == 0) {
        sm[t] = pooled[t];
        __syncthreads();
        const int o = t & 15, kg = t >> 4;
        float pr = 0.0f;
        for (int k = kg; k < HIDDEN; k += 16) pr += sm[k] * Wfc[k * OUT_DIM + o];
        sm[256 + t] = pr;
        __syncthreads();
        if (t < OUT_DIM) {
            float sum = bfc[t];
            #pragma unroll
            for (int gg = 0; gg < 16; ++gg) sum += sm[256 + gg * 16 + t];
            out[t] = sum;
        }
    }
}

extern "C" void kernel_launch(void* const* d_in, const int* in_sizes, int n_in,
                              void* d_out, int out_size, void* d_ws, size_t ws_size,
                              hipStream_t stream) {
    const float* adj = (const float*)d_in[0];
    const float* W1  = (const float*)d_in[1];
    const float* b1  = (const float*)d_in[2];
    const float* W2  = (const float*)d_in[3];
    const float* b2  = (const float*)d_in[4];
    const float* Wfc = (const float*)d_in[5];
    const float* bfc = (const float*)d_in[6];
    float* out = (float*)d_out;

    // workspace layout (16 MiB used)
    char* ws = (char*)d_ws;
    int*   cnt    = (int*)  (ws + 0);               // 32 KB
    float* s      = (float*)(ws + (32 << 10));      // 32 KB
    float* tt     = (float*)(ws + (64 << 10));      // 32 KB
    float* v      = (float*)(ws + (96 << 10));      // 1 KB
    float* pooled = (float*)(ws + (100 << 10));     // 1 KB
    int*   barctr = (int*)  (ws + (104 << 10));     // 640 B (5 x 128 B)
    int*   nbr    = (int*)  (ws + (1 << 20));       // 4 MB
    float* g      = (float*)(ws + (8 << 20));       // 8 MB (slow path only)

    k_reset<<<1, 256, 0, stream>>>(barctr, pooled);
    k_all  <<<NBLK, 256, 0, stream>>>(adj, W1, b1, W2, b2, Wfc, bfc,
                                      cnt, nbr, s, tt, v, pooled, g, barctr, out);
}

// Round 9
// 99.975 us; speedup vs baseline: 4.8973x; 4.8973x over previous
//
#include <hip/hip_runtime.h>

#define N_NODES 8192
#define HIDDEN 256
#define OUT_DIM 16
#define CAP 128                 // max neighbors stored; binomial max deg ~66 << 128
#define NPB 16                  // nodes per block in srowg/qpool
#define PBLK (N_NODES / NPB)    // 512 blocks
#define G_ROWS 16               // slow-path GEMM rows per block (== NPB)

// ---------------- K1: dense row scan -> CSR; v/flag/zeros by 16 extra blocks
__global__ void k_scan(const float* __restrict__ adj, const float* __restrict__ W1,
                       const float* __restrict__ b1, const float* __restrict__ W2,
                       int* __restrict__ cnt, int* __restrict__ nbr,
                       float* __restrict__ v, int* __restrict__ flag,
                       float* __restrict__ pooled, int* __restrict__ donectr) {
    const int t = threadIdx.x;         // 256
    const int bid = blockIdx.x;        // 8192 + 16

    if (bid >= N_NODES) {              // ---- v / flag / zero blocks ----
        const int bv = bid - N_NODES;  // 0..15
        __shared__ float sm[256];
        __shared__ int nz;
        if (t == 0) nz = 0;
        __syncthreads();
        if (bv == 0) {
            pooled[t] = 0.0f;                  // zero accumulators each call
            if (t == 0) *donectr = 0;
            if (b1[t] != 0.0f) atomicOr(&nz, 1);
        }
        const int kg = t >> 4, cl = t & 15;
        const int c = bv * 16 + cl;
        float partial = 0.0f;
        for (int k = kg; k < HIDDEN; k += 16)
            partial += fmaxf(W1[k], 0.0f) * W2[(size_t)k * HIDDEN + c];
        sm[t] = partial;
        __syncthreads();
        if (bv == 0 && t == 0) *flag = (nz == 0) ? 1 : 0;
        if (t < 16) {
            float acc = 0.0f;
            #pragma unroll
            for (int gg = 0; gg < 16; ++gg) acc += sm[gg * 16 + t];
            v[bv * 16 + t] = acc;
        }
        return;
    }

    // ---- row-builder blocks (R2/R7-proven: LDS counter only) ----
    const int i = bid;
    __shared__ int scnt;
    if (t == 0) scnt = 0;
    __syncthreads();
    const uint4* row = (const uint4*)(adj + (size_t)i * N_NODES);
    #pragma unroll
    for (int c8 = 0; c8 < N_NODES / 4 / 256; ++c8) {   // 8 iterations
        uint4 vv = row[c8 * 256 + t];
        int base = (c8 * 256 + t) * 4;
        if (vv.x | vv.y | vv.z | vv.w) {   // adj entries are exactly 0.0f or 1.0f
            if (vv.x && base + 0 != i) { int p = atomicAdd(&scnt, 1); if (p < CAP) nbr[(size_t)i * CAP + p] = base + 0; }
            if (vv.y && base + 1 != i) { int p = atomicAdd(&scnt, 1); if (p < CAP) nbr[(size_t)i * CAP + p] = base + 1; }
            if (vv.z && base + 2 != i) { int p = atomicAdd(&scnt, 1); if (p < CAP) nbr[(size_t)i * CAP + p] = base + 2; }
            if (vv.w && base + 3 != i) { int p = atomicAdd(&scnt, 1); if (p < CAP) nbr[(size_t)i * CAP + p] = base + 3; }
        }
    }
    __syncthreads();
    if (t == 0) cnt[i] = scnt < CAP ? scnt : CAP;
}

// ---------------- K2: s,tt per node-wave; slow-path GEMM fused --------------
__global__ void k_srowg(const int* __restrict__ cnt, const int* __restrict__ nbr,
                        const float* __restrict__ W1, const float* __restrict__ b1,
                        const float* __restrict__ W2, const int* __restrict__ flag,
                        float* __restrict__ s, float* __restrict__ tt,
                        float* __restrict__ g) {
    const int t = threadIdx.x;         // 256
    const int bid = blockIdx.x;        // 512
    const int lane = t & 63;
    const int w = t >> 6;
    __shared__ float sl[NPB];
    __shared__ float hT[HIDDEN][G_ROWS];   // 16 KB (slow path)

    #pragma unroll
    for (int n = 0; n < NPB / 4; ++n) {    // 4 nodes per wave
        const int i = bid * NPB + w * (NPB / 4) + n;
        const int c = cnt[i];
        const float di = rsqrtf((float)(c + 1));   // +1 self loop
        float p = 0.0f;
        for (int k = lane; k < c; k += 64)
            p += rsqrtf((float)(cnt[nbr[(size_t)i * CAP + k]] + 1));
        #pragma unroll
        for (int off = 32; off > 0; off >>= 1) p += __shfl_down(p, off);
        if (lane == 0) {
            const float si = di * (di + p);
            s[i] = si; tt[i] = di * si; sl[w * (NPB / 4) + n] = si;
        }
    }
    if (*flag) return;                 // fast path: done (uniform)

    // ---- SLOW: g rows bid*16..+15 = relu(s (x) W1 + b1) @ W2 ----
    __syncthreads();
    const float w1 = W1[t], bb = b1[t];
    #pragma unroll
    for (int r = 0; r < G_ROWS; ++r)
        hT[t][r] = fmaxf(sl[r] * w1 + bb, 0.0f);
    __syncthreads();
    float acc[G_ROWS];
    #pragma unroll
    for (int r = 0; r < G_ROWS; ++r) acc[r] = 0.0f;
    for (int k = 0; k < HIDDEN; ++k) {
        const float w2 = W2[(size_t)k * HIDDEN + t];
        const float4 h0 = *(const float4*)&hT[k][0];
        const float4 h1 = *(const float4*)&hT[k][4];
        const float4 h2 = *(const float4*)&hT[k][8];
        const float4 h3 = *(const float4*)&hT[k][12];
        acc[0]  += h0.x * w2;  acc[1]  += h0.y * w2;  acc[2]  += h0.z * w2;  acc[3]  += h0.w * w2;
        acc[4]  += h1.x * w2;  acc[5]  += h1.y * w2;  acc[6]  += h1.z * w2;  acc[7]  += h1.w * w2;
        acc[8]  += h2.x * w2;  acc[9]  += h2.y * w2;  acc[10] += h2.z * w2;  acc[11] += h2.w * w2;
        acc[12] += h3.x * w2;  acc[13] += h3.y * w2;  acc[14] += h3.z * w2;  acc[15] += h3.w * w2;
    }
    #pragma unroll
    for (int r = 0; r < G_ROWS; ++r)
        g[(size_t)(bid * NPB + r) * HIDDEN + t] = acc[r];
}

// ---------------- K3: pool; last-done block runs the FC ---------------------
__global__ void k_qpool(const int* __restrict__ cnt, const int* __restrict__ nbr,
                        const float* __restrict__ s, const float* __restrict__ tt,
                        const float* __restrict__ g, const float* __restrict__ v,
                        const float* __restrict__ b2, const int* __restrict__ flag,
                        const float* __restrict__ Wfc, const float* __restrict__ bfc,
                        float* __restrict__ pooled, int* __restrict__ donectr,
                        float* __restrict__ out) {
    const int t = threadIdx.x;         // 256
    const int bid = blockIdx.x;        // 512
    const int lane = t & 63;
    const int w = t >> 6;
    __shared__ float qsh[NPB];
    __shared__ float sm[512];
    __shared__ int lastf;

    float pp = 0.0f;
    if (*flag) {
        // FAST: q_i = di*(di*s_i + sum tt_j) per node-wave; pool relu(q*v+b2)
        #pragma unroll
        for (int n = 0; n < NPB / 4; ++n) {
            const int i = bid * NPB + w * (NPB / 4) + n;
            const int c = cnt[i];
            const float di = rsqrtf((float)(c + 1));
            float p = 0.0f;
            for (int k = lane; k < c; k += 64) p += tt[nbr[(size_t)i * CAP + k]];
            #pragma unroll
            for (int off = 32; off > 0; off >>= 1) p += __shfl_down(p, off);
            if (lane == 0) qsh[w * (NPB / 4) + n] = di * (di * s[i] + p);
        }
        __syncthreads();
        const float vc = v[t], bc = b2[t];
        #pragma unroll
        for (int n = 0; n < NPB; ++n) pp += fmaxf(qsh[n] * vc + bc, 0.0f);
    } else {
        // SLOW: CSR aggregate of g + bias + relu (insurance path)
        const float bc = b2[t];
        for (int n = 0; n < NPB; ++n) {
            const int i = bid * NPB + n;
            const int c = cnt[i];
            const float di = rsqrtf((float)(c + 1));
            float val = di * g[(size_t)i * HIDDEN + t];
            const int* nb = nbr + (size_t)i * CAP;
            for (int k = 0; k < c; ++k) {
                const int j = nb[k];
                val += rsqrtf((float)(cnt[j] + 1)) * g[(size_t)j * HIDDEN + t];
            }
            pp += fmaxf(di * val + bc, 0.0f);
        }
    }
    atomicAdd(&pooled[t], pp);         // fire-and-forget, 64 hot lines
    __threadfence();                   // release my pooled adds
    if (t == 0) lastf = (atomicAdd(donectr, 1) == PBLK - 1);
    __syncthreads();
    if (!lastf) return;

    // ---- last block: all pooled adds are visible (acq-rel chain) ----
    __threadfence();
    sm[t] = __hip_atomic_load(&pooled[t], __ATOMIC_ACQUIRE, __HIP_MEMORY_SCOPE_AGENT);
    __syncthreads();
    const int o = t & 15, kg = t >> 4;
    float pr = 0.0f;
    for (int k = kg; k < HIDDEN; k += 16) pr += sm[k] * Wfc[k * OUT_DIM + o];
    sm[256 + t] = pr;
    __syncthreads();
    if (t < OUT_DIM) {
        float sum = bfc[t];
        #pragma unroll
        for (int gg = 0; gg < 16; ++gg) sum += sm[256 + gg * 16 + t];
        out[t] = sum;
    }
}

extern "C" void kernel_launch(void* const* d_in, const int* in_sizes, int n_in,
                              void* d_out, int out_size, void* d_ws, size_t ws_size,
                              hipStream_t stream) {
    const float* adj = (const float*)d_in[0];
    const float* W1  = (const float*)d_in[1];
    const float* b1  = (const float*)d_in[2];
    const float* W2  = (const float*)d_in[3];
    const float* b2  = (const float*)d_in[4];
    const float* Wfc = (const float*)d_in[5];
    const float* bfc = (const float*)d_in[6];
    float* out = (float*)d_out;

    // workspace layout (16 MiB used)
    char* ws = (char*)d_ws;
    int*   cnt     = (int*)  (ws + 0);              // 32 KB
    float* s       = (float*)(ws + (32 << 10));     // 32 KB
    float* tt      = (float*)(ws + (64 << 10));     // 32 KB
    float* v       = (float*)(ws + (96 << 10));     // 1 KB
    int*   flag    = (int*)  (ws + (100 << 10));    // 4 B
    float* pooled  = (float*)(ws + (104 << 10));    // 1 KB
    int*   donectr = (int*)  (ws + (108 << 10));    // 4 B
    int*   nbr     = (int*)  (ws + (1 << 20));      // 4 MB
    float* g       = (float*)(ws + (8 << 20));      // 8 MB (slow path only)

    k_scan <<<N_NODES + 16, 256, 0, stream>>>(adj, W1, b1, W2, cnt, nbr, v, flag,
                                              pooled, donectr);
    k_srowg<<<PBLK, 256, 0, stream>>>(cnt, nbr, W1, b1, W2, flag, s, tt, g);
    k_qpool<<<PBLK, 256, 0, stream>>>(cnt, nbr, s, tt, g, v, b2, flag, Wfc, bfc,
                                      pooled, donectr, out);
}

// Round 10
// 65.479 us; speedup vs baseline: 7.4773x; 1.5268x over previous
//
#include <hip/hip_runtime.h>

#define N_NODES 8192
#define HIDDEN 256
#define OUT_DIM 16
#define CAP 128                 // max neighbors stored; binomial max deg ~66 << 128
#define G_ROWS 16               // rows per block in the slow dense GEMM
#define PF_BLK 64               // pool blocks -> P2[64][256] = 64 KB
#define PF_N (N_NODES / PF_BLK) // 128 nodes per pool block

// ---------------- K1: dense row scan -> CSR; v/flag by 16 aux blocks --------
// R2/R7-proven: each block owns one row; the ONLY atomic is the LDS counter.
__global__ void k_scan(const float* __restrict__ adj, const float* __restrict__ W1,
                       const float* __restrict__ b1, const float* __restrict__ W2,
                       int* __restrict__ cnt, int* __restrict__ nbr,
                       float* __restrict__ v, int* __restrict__ flag) {
    const int t = threadIdx.x;         // 256
    const int bid = blockIdx.x;        // 8192 + 16

    if (bid >= N_NODES) {              // ---- v / flag blocks (16 CUs) ----
        const int bv = bid - N_NODES;  // 0..15
        __shared__ float sm[256];
        __shared__ int nz;
        if (t == 0) nz = 0;
        __syncthreads();
        if (bv == 0 && b1[t] != 0.0f) atomicOr(&nz, 1);
        const int kg = t >> 4, cl = t & 15;
        const int c = bv * 16 + cl;
        float partial = 0.0f;
        for (int k = kg; k < HIDDEN; k += 16)
            partial += fmaxf(W1[k], 0.0f) * W2[(size_t)k * HIDDEN + c];
        sm[t] = partial;
        __syncthreads();
        if (bv == 0 && t == 0) *flag = (nz == 0) ? 1 : 0;
        if (t < 16) {
            float acc = 0.0f;
            #pragma unroll
            for (int gg = 0; gg < 16; ++gg) acc += sm[gg * 16 + t];
            v[bv * 16 + t] = acc;
        }
        return;
    }

    // ---- row-builder blocks ----
    const int i = bid;
    __shared__ int scnt;
    if (t == 0) scnt = 0;
    __syncthreads();
    const uint4* row = (const uint4*)(adj + (size_t)i * N_NODES);
    #pragma unroll
    for (int c8 = 0; c8 < N_NODES / 4 / 256; ++c8) {   // 8 iterations
        uint4 vv = row[c8 * 256 + t];
        int base = (c8 * 256 + t) * 4;
        if (vv.x | vv.y | vv.z | vv.w) {   // adj entries are exactly 0.0f or 1.0f
            if (vv.x && base + 0 != i) { int p = atomicAdd(&scnt, 1); if (p < CAP) nbr[(size_t)i * CAP + p] = base + 0; }
            if (vv.y && base + 1 != i) { int p = atomicAdd(&scnt, 1); if (p < CAP) nbr[(size_t)i * CAP + p] = base + 1; }
            if (vv.z && base + 2 != i) { int p = atomicAdd(&scnt, 1); if (p < CAP) nbr[(size_t)i * CAP + p] = base + 2; }
            if (vv.w && base + 3 != i) { int p = atomicAdd(&scnt, 1); if (p < CAP) nbr[(size_t)i * CAP + p] = base + 3; }
        }
    }
    __syncthreads();
    if (t == 0) cnt[i] = scnt < CAP ? scnt : CAP;
}

// ---------------- K2: s_i = di*(di + sum dinv_j); tt_i = di*s_i -------------
// R2-proven shape: 2048 blocks, one node per wave.
__global__ void k_srow(const int* __restrict__ cnt, const int* __restrict__ nbr,
                       float* __restrict__ s, float* __restrict__ tt) {
    const int w = threadIdx.x >> 6;
    const int lane = threadIdx.x & 63;
    const int i = blockIdx.x * 4 + w;
    const int c = cnt[i];
    const float di = rsqrtf((float)(c + 1));   // +1 self loop
    float p = 0.0f;
    for (int k = lane; k < c; k += 64)
        p += rsqrtf((float)(cnt[nbr[(size_t)i * CAP + k]] + 1));
    #pragma unroll
    for (int off = 32; off > 0; off >>= 1) p += __shfl_down(p, off);
    if (lane == 0) {
        const float si = di * (di + p);
        s[i] = si; tt[i] = di * si;
    }
}

// ---------------- K3: FAST q per node-wave | SLOW GEMM (blocks < 512) -------
__global__ void k_qg(const int* __restrict__ cnt, const int* __restrict__ nbr,
                     const float* __restrict__ s, const float* __restrict__ tt,
                     const float* __restrict__ W1, const float* __restrict__ b1,
                     const float* __restrict__ W2, const int* __restrict__ flag,
                     float* __restrict__ q, float* __restrict__ g) {
    const int t = threadIdx.x;
    if (*flag) {
        // q_i = di*(di*s_i + sum tt_j), one node per wave (2048 blocks x 4)
        const int w = t >> 6, lane = t & 63;
        const int i = blockIdx.x * 4 + w;
        const int c = cnt[i];
        const float di = rsqrtf((float)(c + 1));
        float p = 0.0f;
        for (int k = lane; k < c; k += 64) p += tt[nbr[(size_t)i * CAP + k]];
        #pragma unroll
        for (int off = 32; off > 0; off >>= 1) p += __shfl_down(p, off);
        if (lane == 0) q[i] = di * (di * s[i] + p);
        return;
    }
    // SLOW: g = relu(s (x) W1 + b1) @ W2 ; s[] is complete (k_srow done)
    if (blockIdx.x >= N_NODES / G_ROWS) return;
    const int row0 = blockIdx.x * G_ROWS;
    __shared__ float hT[HIDDEN][G_ROWS];
    const float w1 = W1[t], bb = b1[t];
    for (int r = 0; r < G_ROWS; ++r)
        hT[t][r] = fmaxf(s[row0 + r] * w1 + bb, 0.0f);
    __syncthreads();
    float acc[G_ROWS];
    #pragma unroll
    for (int r = 0; r < G_ROWS; ++r) acc[r] = 0.0f;
    for (int k = 0; k < HIDDEN; ++k) {
        const float w2 = W2[(size_t)k * HIDDEN + t];
        const float4 h0 = *(const float4*)&hT[k][0];
        const float4 h1 = *(const float4*)&hT[k][4];
        const float4 h2 = *(const float4*)&hT[k][8];
        const float4 h3 = *(const float4*)&hT[k][12];
        acc[0]  += h0.x * w2;  acc[1]  += h0.y * w2;  acc[2]  += h0.z * w2;  acc[3]  += h0.w * w2;
        acc[4]  += h1.x * w2;  acc[5]  += h1.y * w2;  acc[6]  += h1.z * w2;  acc[7]  += h1.w * w2;
        acc[8]  += h2.x * w2;  acc[9]  += h2.y * w2;  acc[10] += h2.z * w2;  acc[11] += h2.w * w2;
        acc[12] += h3.x * w2;  acc[13] += h3.y * w2;  acc[14] += h3.z * w2;  acc[15] += h3.w * w2;
    }
    #pragma unroll
    for (int r = 0; r < G_ROWS; ++r)
        g[(size_t)(row0 + r) * HIDDEN + t] = acc[r];
}

// ---------------- K4: pool partials -> P2[64][256]; both paths write --------
__global__ void k_pool(const int* __restrict__ cnt, const int* __restrict__ nbr,
                       const float* __restrict__ q, const float* __restrict__ g,
                       const float* __restrict__ v, const float* __restrict__ b2,
                       const int* __restrict__ flag, float* __restrict__ P2) {
    const int t = threadIdx.x;
    const int bid = blockIdx.x;            // 64
    if (*flag) {
        const float vc = v[t], bc = b2[t];
        const int i0 = bid * PF_N;
        float pp = 0.0f;
        #pragma unroll 8
        for (int n = 0; n < PF_N; ++n)             // q load: wave-uniform, L1/L2
            pp += fmaxf(q[i0 + n] * vc + bc, 0.0f);
        P2[(size_t)bid * HIDDEN + t] = pp;
    } else {
        const float bc = b2[t];
        float pool = 0.0f;
        for (int n = 0; n < PF_N; ++n) {
            const int i = bid * PF_N + n;
            const int c = cnt[i];
            const float di = rsqrtf((float)(c + 1));
            float val = di * g[(size_t)i * HIDDEN + t];
            const int* nb = nbr + (size_t)i * CAP;
            for (int k = 0; k < c; ++k) {
                const int j = nb[k];
                val += rsqrtf((float)(cnt[j] + 1)) * g[(size_t)j * HIDDEN + t];
            }
            pool += fmaxf(di * val + bc, 0.0f);
        }
        P2[(size_t)bid * HIDDEN + t] = pool;
    }
}

// ---------------- K5: pooled = sum P2 (64 KB); out = pooled @ Wfc + bfc -----
__global__ void k_finish(const float* __restrict__ P2, const float* __restrict__ Wfc,
                         const float* __restrict__ bfc, float* __restrict__ out) {
    const int t = threadIdx.x;      // 256
    float a0 = 0.f, a1 = 0.f, a2 = 0.f, a3 = 0.f;
    #pragma unroll
    for (int r = 0; r < PF_BLK; r += 4) {
        a0 += P2[(size_t)(r + 0) * HIDDEN + t];
        a1 += P2[(size_t)(r + 1) * HIDDEN + t];
        a2 += P2[(size_t)(r + 2) * HIDDEN + t];
        a3 += P2[(size_t)(r + 3) * HIDDEN + t];
    }
    __shared__ float pooled[HIDDEN];
    pooled[t] = (a0 + a1) + (a2 + a3);
    __syncthreads();
    const int o = t & 15, kg = t >> 4;
    float pr = 0.0f;
    for (int k = kg; k < HIDDEN; k += 16) pr += pooled[k] * Wfc[k * OUT_DIM + o];
    __shared__ float red[256];
    red[t] = pr;
    __syncthreads();
    if (t < OUT_DIM) {
        float sum = bfc[t];
        #pragma unroll
        for (int gg = 0; gg < 16; ++gg) sum += red[gg * 16 + t];
        out[t] = sum;
    }
}

extern "C" void kernel_launch(void* const* d_in, const int* in_sizes, int n_in,
                              void* d_out, int out_size, void* d_ws, size_t ws_size,
                              hipStream_t stream) {
    const float* adj = (const float*)d_in[0];
    const float* W1  = (const float*)d_in[1];
    const float* b1  = (const float*)d_in[2];
    const float* W2  = (const float*)d_in[3];
    const float* b2  = (const float*)d_in[4];
    const float* Wfc = (const float*)d_in[5];
    const float* bfc = (const float*)d_in[6];
    float* out = (float*)d_out;

    // workspace layout (16 MiB used)
    char* ws = (char*)d_ws;
    int*   cnt  = (int*)  (ws + 0);                 // 32 KB
    float* s    = (float*)(ws + (32 << 10));        // 32 KB
    float* tt   = (float*)(ws + (64 << 10));        // 32 KB
    float* v    = (float*)(ws + (96 << 10));        // 1 KB
    int*   flag = (int*)  (ws + (100 << 10));       // 4 B
    float* q    = (float*)(ws + (104 << 10));       // 32 KB
    float* P2   = (float*)(ws + (192 << 10));       // 64 KB (64 x 256)
    int*   nbr  = (int*)  (ws + (1 << 20));         // 4 MB
    float* g    = (float*)(ws + (8 << 20));         // 8 MB (slow path only)

    k_scan  <<<N_NODES + 16, 256, 0, stream>>>(adj, W1, b1, W2, cnt, nbr, v, flag);
    k_srow  <<<N_NODES / 4, 256, 0, stream>>>(cnt, nbr, s, tt);
    k_qg    <<<N_NODES / 4, 256, 0, stream>>>(cnt, nbr, s, tt, W1, b1, W2, flag, q, g);
    k_pool  <<<PF_BLK, 256, 0, stream>>>(cnt, nbr, q, g, v, b2, flag, P2);
    k_finish<<<1, 256, 0, stream>>>(P2, Wfc, bfc, out);
}